// Round 4
// baseline (38256.845 us; speedup 1.0000x reference)
//
#include <hip/hip_runtime.h>
#include <math.h>

#define TSTEPS 512
#define BSZ    64
#define EDIM   512
#define HDIM   1024
#define KDIM   1536
#define NBLK   256
#define KW     384          // K-slice per wave
#define APLANE 98304        // 64*1536 elements per (buf, hi|lo) plane

typedef __bf16 bf16x8 __attribute__((ext_vector_type(8)));
typedef float  f32x4  __attribute__((ext_vector_type(4)));
typedef unsigned short ushort8 __attribute__((ext_vector_type(8)));
typedef unsigned int uint;

__device__ __forceinline__ unsigned short rne_bf16(float f) {
    uint u = __float_as_uint(f);
    return (unsigned short)((u + 0x7fffu + ((u >> 16) & 1u)) >> 16);
}
__device__ __forceinline__ float bf2f(unsigned short s) {
    return __uint_as_float(((uint)s) << 16);
}

// Slot-based grid barrier. Poison-proof (polls == phase with phase in [1,513]),
// overtake-proof (go-flag gating: gatherer observes every slot at phase p
// before any block can pass p).
__device__ __forceinline__ void gridbar(uint* __restrict__ bar,
                                        uint* __restrict__ go, uint phase) {
    __syncthreads();
    __threadfence();   // release: drain this block's writes to agent scope
    if (threadIdx.x == 0)
        __hip_atomic_store(&bar[blockIdx.x], phase,
                           __ATOMIC_RELEASE, __HIP_MEMORY_SCOPE_AGENT);
    if (blockIdx.x == 0) {
        while (__hip_atomic_load(&bar[threadIdx.x],
                                 __ATOMIC_ACQUIRE, __HIP_MEMORY_SCOPE_AGENT) != phase)
            __builtin_amdgcn_s_sleep(2);
        __syncthreads();
        if (threadIdx.x == 0)
            __hip_atomic_store(go, phase,
                               __ATOMIC_RELEASE, __HIP_MEMORY_SCOPE_AGENT);
    }
    if (threadIdx.x == 0) {
        while (__hip_atomic_load(go, __ATOMIC_ACQUIRE,
                                 __HIP_MEMORY_SCOPE_AGENT) != phase)
            __builtin_amdgcn_s_sleep(2);
    }
    __syncthreads();
    __threadfence();   // acquire side: invalidate caches before reading new A
}

__global__ __launch_bounds__(256, 1) void lstm_persist(
    const float* __restrict__ x,                       // [T,B,E]
    const float* __restrict__ Wi, const float* __restrict__ Wo,
    const float* __restrict__ Wf, const float* __restrict__ Wm,  // [KDIM,HDIM]
    const float* __restrict__ bi, const float* __restrict__ bo,
    const float* __restrict__ bfp, const float* __restrict__ bm, // [HDIM]
    float* __restrict__ out,                           // [B,T,H]
    __bf16* __restrict__ abase,                        // 4 planes of APLANE
    uint* __restrict__ bar, uint* __restrict__ go)
{
    __shared__ float zbuf[4][64][17];   // [wave][row][16 cols + pad]

    const int tid  = threadIdx.x;
    const int blk  = blockIdx.x;
    const int lane = tid & 63;
    const int w    = tid >> 6;          // wave id = K-slice id
    const int l15  = lane & 15;
    const int q    = lane >> 4;

    // ---- load W (hi/lo split) into registers: 96 VGPR/lane ----
    // lane col cl=l15 -> gate g=cl>>2, local col j=cl&3, W column c=blk*4+j
    const int g = l15 >> 2, j = l15 & 3, c = blk * 4 + j;
    const float* Wg = (g == 0) ? Wi : (g == 1) ? Wo : (g == 2) ? Wf : Wm;
    bf16x8 wh[12], wl[12];
    #pragma unroll
    for (int kk = 0; kk < 12; ++kk) {
        ushort8 uh, ul;
        #pragma unroll
        for (int e = 0; e < 8; ++e) {
            const int k = w * KW + kk * 32 + q * 8 + e;
            const float v = Wg[(size_t)k * HDIM + c];
            const unsigned short hb = rne_bf16(v);
            uh[e] = hb;
            ul[e] = rne_bf16(v - bf2f(hb));
        }
        wh[kk] = __builtin_bit_cast(bf16x8, uh);
        wl[kk] = __builtin_bit_cast(bf16x8, ul);
    }

    // ---- per-thread gate mapping ----
    const int gb  = tid >> 2;           // batch row 0..63
    const int gj  = tid & 3;            // local h-col
    const int ghc = blk * 4 + gj;       // global h-col
    float bia[4];
    bia[0] = bi[ghc]; bia[1] = bo[ghc]; bia[2] = bfp[ghc]; bia[3] = bm[ghc];
    float c_reg = 0.0f;

    // ---- init A[0]: x0 (hi/lo) + h0 = 0 ----
    {
        __bf16* AH0 = abase;
        __bf16* AL0 = abase + APLANE;
        if (tid < 128) {
            const int flat = blk * 128 + tid;       // b*512+e over [64][512]
            const int b = flat >> 9, e = flat & 511;
            const float v = x[flat];                // t = 0
            const unsigned short xh = rne_bf16(v);
            AH0[b * KDIM + e] = __builtin_bit_cast(__bf16, xh);
            AL0[b * KDIM + e] = __builtin_bit_cast(__bf16, rne_bf16(v - bf2f(xh)));
        }
        const int flat2 = blk * 256 + tid;          // b*1024+hc over [64][1024]
        const int b2 = flat2 >> 10, hc2 = flat2 & 1023;
        AH0[b2 * KDIM + 512 + hc2] = __builtin_bit_cast(__bf16, (unsigned short)0);
        AL0[b2 * KDIM + 512 + hc2] = __builtin_bit_cast(__bf16, (unsigned short)0);
    }
    gridbar(bar, go, 1u);

    // ---- time loop ----
    for (int t = 0; t < TSTEPS; ++t) {
        const int cur = t & 1, nxt = cur ^ 1;
        const __bf16* AH = abase + (size_t)(2 * cur) * APLANE;
        const __bf16* AL = AH + APLANE;
        __bf16* AHn = abase + (size_t)(2 * nxt) * APLANE;
        __bf16* ALn = AHn + APLANE;

        // compute: wave w handles all 64 rows x 16 cols x k in [w*384,+384)
        f32x4 acc[4];
        #pragma unroll
        for (int m = 0; m < 4; ++m) acc[m] = (f32x4){0.f, 0.f, 0.f, 0.f};

        #pragma unroll
        for (int kk = 0; kk < 12; ++kk) {
            const int kof = w * KW + kk * 32 + q * 8;
            bf16x8 ah[4], al[4];
            #pragma unroll
            for (int m = 0; m < 4; ++m) {
                const int row = m * 16 + l15;
                ah[m] = *reinterpret_cast<const bf16x8*>(&AH[row * KDIM + kof]);
                al[m] = *reinterpret_cast<const bf16x8*>(&AL[row * KDIM + kof]);
            }
            #pragma unroll
            for (int m = 0; m < 4; ++m) {
                acc[m] = __builtin_amdgcn_mfma_f32_16x16x32_bf16(ah[m], wh[kk], acc[m], 0, 0, 0);
                acc[m] = __builtin_amdgcn_mfma_f32_16x16x32_bf16(ah[m], wl[kk], acc[m], 0, 0, 0);
                acc[m] = __builtin_amdgcn_mfma_f32_16x16x32_bf16(al[m], wh[kk], acc[m], 0, 0, 0);
            }
        }

        // partials -> LDS  (C layout: col=lane&15, row=(lane>>4)*4+r)
        __syncthreads();
        #pragma unroll
        for (int m = 0; m < 4; ++m)
            #pragma unroll
            for (int r = 0; r < 4; ++r)
                zbuf[w][m * 16 + q * 4 + r][l15] = acc[m][r];
        __syncthreads();

        // gates: thread (gb, gj) -> h-col ghc
        float z[4];
        #pragma unroll
        for (int gg = 0; gg < 4; ++gg) {
            z[gg] = zbuf[0][gb][gg * 4 + gj] + zbuf[1][gb][gg * 4 + gj]
                  + zbuf[2][gb][gg * 4 + gj] + zbuf[3][gb][gg * 4 + gj] + bia[gg];
        }
        const float ig = 1.0f / (1.0f + expf(-z[0]));
        const float og = 1.0f / (1.0f + expf(-z[1]));
        const float fg = 1.0f / (1.0f + expf(-z[2]));
        const float mg = tanhf(z[3]);
        c_reg = fg * c_reg + ig * mg;
        const float hv = og * tanhf(c_reg);
        out[((size_t)gb * TSTEPS + t) * HDIM + ghc] = hv;

        const unsigned short hh = rne_bf16(hv);
        AHn[gb * KDIM + 512 + ghc] = __builtin_bit_cast(__bf16, hh);
        ALn[gb * KDIM + 512 + ghc] = __builtin_bit_cast(__bf16, rne_bf16(hv - bf2f(hh)));

        // convert x[t+1] into next A buffer
        if (t < TSTEPS - 1) {
            if (tid < 128) {
                const int flat = blk * 128 + tid;
                const int b = flat >> 9, e = flat & 511;
                const float v = x[(size_t)(t + 1) * (BSZ * EDIM) + flat];
                const unsigned short xh = rne_bf16(v);
                AHn[b * KDIM + e] = __builtin_bit_cast(__bf16, xh);
                ALn[b * KDIM + e] = __builtin_bit_cast(__bf16, rne_bf16(v - bf2f(xh)));
            }
            gridbar(bar, go, (uint)(t + 2));
        }
    }
}

extern "C" void kernel_launch(void* const* d_in, const int* in_sizes, int n_in,
                              void* d_out, int out_size, void* d_ws, size_t ws_size,
                              hipStream_t stream) {
    const float* x   = (const float*)d_in[0];
    const float* Wi  = (const float*)d_in[1];
    const float* bi  = (const float*)d_in[2];
    const float* Wo  = (const float*)d_in[3];
    const float* bo  = (const float*)d_in[4];
    const float* Wf  = (const float*)d_in[5];
    const float* bfp = (const float*)d_in[6];
    const float* Wm  = (const float*)d_in[7];
    const float* bm  = (const float*)d_in[8];
    float* out = (float*)d_out;

    // ws: 4 bf16 planes (A double-buffer hi/lo, 786,432 B) + barrier slots
    __bf16* abase = (__bf16*)d_ws;
    uint*   bar   = (uint*)((char*)d_ws + 4 * (size_t)APLANE * 2);
    uint*   go    = bar + NBLK;

    lstm_persist<<<NBLK, 256, 0, stream>>>(
        x, Wi, Wo, Wf, Wm, bi, bo, bfp, bm, out, abase, bar, go);
}

// Round 5
// 16128.656 us; speedup vs baseline: 2.3720x; 2.3720x over previous
//
#include <hip/hip_runtime.h>
#include <math.h>

#define TSTEPS 512
#define BSZ    64
#define EDIM   512
#define HDIM   1024
#define KDIM   1536
#define NBLK   128
#define KW     384            // K-slice per wave
#define APLANE 98304          // 64*1536 elements per (buf, hi|lo) plane

// sync region (uints): per-phase padded counters, zeroed by prologue
#define SUB_U  ((TSTEPS + 2) * 8 * 32)
#define SUP_U  ((TSTEPS + 2) * 32)
#define GO_U   (8 * 32)

typedef __bf16 bf16x8 __attribute__((ext_vector_type(8)));
typedef float  f32x4  __attribute__((ext_vector_type(4)));
typedef unsigned short ushort8 __attribute__((ext_vector_type(8)));
typedef unsigned int uint;

__device__ __forceinline__ unsigned short rne_bf16(float f) {
    uint u = __float_as_uint(f);
    return (unsigned short)((u + 0x7fffu + ((u >> 16) & 1u)) >> 16);
}
__device__ __forceinline__ float bf2f(unsigned short s) {
    return __uint_as_float(((uint)s) << 16);
}

__global__ __launch_bounds__(256) void zero_sync(uint* __restrict__ p) {
    const int i = blockIdx.x * 256 + threadIdx.x;
    if (i < SUB_U + SUP_U + GO_U) p[i] = 0u;
}

// Two-level grid barrier. Per-phase counters (no reset/ABA), padded lines,
// RELAXED polling with backoff, exactly one ACQUIRE per barrier exit.
__device__ __forceinline__ void gridbar(uint* __restrict__ SUB,
                                        uint* __restrict__ SUP,
                                        uint* __restrict__ GO, uint phase) {
    __syncthreads();
    if (threadIdx.x == 0) {
        const uint g = blockIdx.x & 7u;
        uint o = __hip_atomic_fetch_add(&SUB[(phase * 8u + g) * 32u], 1u,
                                        __ATOMIC_ACQ_REL, __HIP_MEMORY_SCOPE_AGENT);
        if (o == (NBLK / 8 - 1)) {
            uint s = __hip_atomic_fetch_add(&SUP[phase * 32u], 1u,
                                            __ATOMIC_ACQ_REL, __HIP_MEMORY_SCOPE_AGENT);
            if (s == 7u) {
                #pragma unroll
                for (int i = 0; i < 8; ++i)
                    __hip_atomic_store(&GO[i * 32], phase,
                                       __ATOMIC_RELEASE, __HIP_MEMORY_SCOPE_AGENT);
            }
        }
        uint* myg = &GO[g * 32u];
        while (__hip_atomic_load(myg, __ATOMIC_RELAXED,
                                 __HIP_MEMORY_SCOPE_AGENT) < phase)
            __builtin_amdgcn_s_sleep(8);
        (void)__hip_atomic_load(myg, __ATOMIC_ACQUIRE,
                                __HIP_MEMORY_SCOPE_AGENT);
    }
    __syncthreads();
}

// 128 blocks x 256 thr (4 waves). Block bx owns h-cols [bx*8, bx*8+8) x 4 gates
// = 32 N-cols, full K=1536 (wave w covers k in [w*384,+384)).
// W (hi/lo bf16 split) lives in ~192 VGPR/lane for the whole kernel.
__global__ __launch_bounds__(256, 1) void lstm_persist(
    const float* __restrict__ x,                       // [T,B,E]
    const float* __restrict__ Wi, const float* __restrict__ Wo,
    const float* __restrict__ Wf, const float* __restrict__ Wm,  // [KDIM,HDIM]
    const float* __restrict__ bi, const float* __restrict__ bo,
    const float* __restrict__ bfp, const float* __restrict__ bm, // [HDIM]
    float* __restrict__ out,                           // [B,T,H]
    __bf16* __restrict__ abase,                        // 4 planes of APLANE
    uint* __restrict__ SUB, uint* __restrict__ SUP, uint* __restrict__ GO)
{
    __shared__ float zbuf[4][64][33];   // [wave][row][32 cols + pad]

    const int tid  = threadIdx.x;
    const int bx   = blockIdx.x;
    const int lane = tid & 63;
    const int w    = tid >> 6;          // wave id = K-slice id
    const int l15  = lane & 15;
    const int q    = lane >> 4;

    // ---- load W (hi/lo split) into registers ----
    // n-tile 0: c_local = l15      -> gate g0 = l15>>3      (0 or 1)
    // n-tile 1: c_local = 16 + l15 -> gate g0+2             (2 or 3)
    const int g0  = l15 >> 3, j = l15 & 7;
    const int col = bx * 8 + j;
    const float* Wg0 = (g0 == 0) ? Wi : Wo;
    const float* Wg1 = (g0 == 0) ? Wf : Wm;
    bf16x8 wh0[12], wl0[12], wh1[12], wl1[12];
    #pragma unroll
    for (int kk = 0; kk < 12; ++kk) {
        ushort8 uh0, ul0, uh1, ul1;
        #pragma unroll
        for (int e = 0; e < 8; ++e) {
            const int k = w * KW + kk * 32 + q * 8 + e;
            const float v0 = Wg0[(size_t)k * HDIM + col];
            const float v1 = Wg1[(size_t)k * HDIM + col];
            const unsigned short h0 = rne_bf16(v0);
            const unsigned short h1 = rne_bf16(v1);
            uh0[e] = h0; ul0[e] = rne_bf16(v0 - bf2f(h0));
            uh1[e] = h1; ul1[e] = rne_bf16(v1 - bf2f(h1));
        }
        wh0[kk] = __builtin_bit_cast(bf16x8, uh0);
        wl0[kk] = __builtin_bit_cast(bf16x8, ul0);
        wh1[kk] = __builtin_bit_cast(bf16x8, uh1);
        wl1[kk] = __builtin_bit_cast(bf16x8, ul1);
    }

    // ---- per-thread gate mapping: 2 outputs (rows gb, gb+32; col ghc) ----
    const int gb  = tid >> 3;           // 0..31
    const int gj  = tid & 7;
    const int ghc = bx * 8 + gj;
    float bia[4];
    bia[0] = bi[ghc]; bia[1] = bo[ghc]; bia[2] = bfp[ghc]; bia[3] = bm[ghc];
    float c0 = 0.0f, c1 = 0.0f;

    // ---- init A[0]: x0 (hi/lo) + h0 = 0 ----
    {
        __bf16* AH0 = abase;
        __bf16* AL0 = abase + APLANE;
        const int flat = bx * 256 + tid;          // [64][512] x-part
        const int b = flat >> 9, e = flat & 511;
        const float v = x[flat];                  // t = 0
        const unsigned short xh = rne_bf16(v);
        AH0[b * KDIM + e] = __builtin_bit_cast(__bf16, xh);
        AL0[b * KDIM + e] = __builtin_bit_cast(__bf16, rne_bf16(v - bf2f(xh)));
        #pragma unroll
        for (int r = 0; r < 2; ++r) {             // [64][1024] h-part = 0
            const int f2 = bx * 512 + r * 256 + tid;
            const int b2 = f2 >> 10, hc2 = f2 & 1023;
            AH0[b2 * KDIM + 512 + hc2] = __builtin_bit_cast(__bf16, (unsigned short)0);
            AL0[b2 * KDIM + 512 + hc2] = __builtin_bit_cast(__bf16, (unsigned short)0);
        }
    }
    gridbar(SUB, SUP, GO, 1u);

    // ---- time loop ----
    for (int t = 0; t < TSTEPS; ++t) {
        const int cur = t & 1;
        const __bf16* AH = abase + (size_t)(2 * cur) * APLANE;
        const __bf16* AL = AH + APLANE;
        __bf16* AHn = abase + (size_t)(2 * (cur ^ 1)) * APLANE;
        __bf16* ALn = AHn + APLANE;

        // x[t+1] -> next A buffer (overlaps with MFMA below; safe: no block
        // can be 2 steps ahead, so nobody still reads AHn)
        if (t + 1 < TSTEPS) {
            const int flat = bx * 256 + tid;
            const int b = flat >> 9, e = flat & 511;
            const float v = x[(size_t)(t + 1) * (BSZ * EDIM) + flat];
            const unsigned short xh = rne_bf16(v);
            AHn[b * KDIM + e] = __builtin_bit_cast(__bf16, xh);
            ALn[b * KDIM + e] = __builtin_bit_cast(__bf16, rne_bf16(v - bf2f(xh)));
        }

        // MFMA: 4 m-tiles x 2 n-tiles, 3-term hi/lo
        f32x4 acc[4][2];
        #pragma unroll
        for (int m = 0; m < 4; ++m)
            #pragma unroll
            for (int nt = 0; nt < 2; ++nt) acc[m][nt] = (f32x4){0.f, 0.f, 0.f, 0.f};

        #pragma unroll
        for (int kk = 0; kk < 12; ++kk) {
            const int kof = w * KW + kk * 32 + q * 8;
            bf16x8 ah[4], al[4];
            #pragma unroll
            for (int m = 0; m < 4; ++m) {
                const int row = m * 16 + l15;
                ah[m] = *reinterpret_cast<const bf16x8*>(&AH[row * KDIM + kof]);
                al[m] = *reinterpret_cast<const bf16x8*>(&AL[row * KDIM + kof]);
            }
            #pragma unroll
            for (int m = 0; m < 4; ++m) {
                acc[m][0] = __builtin_amdgcn_mfma_f32_16x16x32_bf16(ah[m], wh0[kk], acc[m][0], 0, 0, 0);
                acc[m][1] = __builtin_amdgcn_mfma_f32_16x16x32_bf16(ah[m], wh1[kk], acc[m][1], 0, 0, 0);
                acc[m][0] = __builtin_amdgcn_mfma_f32_16x16x32_bf16(ah[m], wl0[kk], acc[m][0], 0, 0, 0);
                acc[m][1] = __builtin_amdgcn_mfma_f32_16x16x32_bf16(ah[m], wl1[kk], acc[m][1], 0, 0, 0);
                acc[m][0] = __builtin_amdgcn_mfma_f32_16x16x32_bf16(al[m], wh0[kk], acc[m][0], 0, 0, 0);
                acc[m][1] = __builtin_amdgcn_mfma_f32_16x16x32_bf16(al[m], wh1[kk], acc[m][1], 0, 0, 0);
            }
        }

        // partials -> LDS  (C layout: col=lane&15, row=(lane>>4)*4+r; verified r4)
        __syncthreads();
        #pragma unroll
        for (int m = 0; m < 4; ++m)
            #pragma unroll
            for (int nt = 0; nt < 2; ++nt)
                #pragma unroll
                for (int r = 0; r < 4; ++r)
                    zbuf[w][m * 16 + q * 4 + r][nt * 16 + l15] = acc[m][nt][r];
        __syncthreads();

        // gates: 2 outputs per thread (rows gb, gb+32)
        #pragma unroll
        for (int half = 0; half < 2; ++half) {
            const int b = gb + half * 32;
            float z[4];
            #pragma unroll
            for (int gg = 0; gg < 4; ++gg)
                z[gg] = zbuf[0][b][gg * 8 + gj] + zbuf[1][b][gg * 8 + gj]
                      + zbuf[2][b][gg * 8 + gj] + zbuf[3][b][gg * 8 + gj] + bia[gg];
            const float ig = 1.0f / (1.0f + expf(-z[0]));
            const float og = 1.0f / (1.0f + expf(-z[1]));
            const float fg = 1.0f / (1.0f + expf(-z[2]));
            const float mg = tanhf(z[3]);
            float& cr = half ? c1 : c0;
            cr = fg * cr + ig * mg;
            const float hv = og * tanhf(cr);
            out[((size_t)b * TSTEPS + t) * HDIM + ghc] = hv;
            const unsigned short hh = rne_bf16(hv);
            AHn[b * KDIM + 512 + ghc] = __builtin_bit_cast(__bf16, hh);
            ALn[b * KDIM + 512 + ghc] = __builtin_bit_cast(__bf16, rne_bf16(hv - bf2f(hh)));
        }

        if (t + 1 < TSTEPS) gridbar(SUB, SUP, GO, (uint)(t + 2));
    }
}

extern "C" void kernel_launch(void* const* d_in, const int* in_sizes, int n_in,
                              void* d_out, int out_size, void* d_ws, size_t ws_size,
                              hipStream_t stream) {
    const float* x   = (const float*)d_in[0];
    const float* Wi  = (const float*)d_in[1];
    const float* bi  = (const float*)d_in[2];
    const float* Wo  = (const float*)d_in[3];
    const float* bo  = (const float*)d_in[4];
    const float* Wf  = (const float*)d_in[5];
    const float* bfp = (const float*)d_in[6];
    const float* Wm  = (const float*)d_in[7];
    const float* bm  = (const float*)d_in[8];
    float* out = (float*)d_out;

    // ws: 4 bf16 A-planes (786,432 B) | SUB | SUP | GO  (~1.4 MB total)
    __bf16* abase = (__bf16*)d_ws;
    uint*   SUB   = (uint*)((char*)d_ws + 4 * (size_t)APLANE * 2);
    uint*   SUP   = SUB + SUB_U;
    uint*   GO    = SUP + SUP_U;

    const int zn = SUB_U + SUP_U + GO_U;
    zero_sync<<<(zn + 255) / 256, 256, 0, stream>>>(SUB);

    lstm_persist<<<NBLK, 256, 0, stream>>>(
        x, Wi, Wo, Wf, Wm, bi, bo, bfp, bm, out, abase, SUB, SUP, GO);
}

// Round 7
// 12664.042 us; speedup vs baseline: 3.0209x; 1.2736x over previous
//
#include <hip/hip_runtime.h>
#include <math.h>

#define TSTEPS 512
#define BSZ    64
#define EDIM   512
#define HDIM   1024
#define KDIM   1536
#define NBLK   128
#define KW     384            // K-slice per wave
#define APLANE 98304          // 64*1536 elements per (buf, hi|lo) plane

// sync region (uints): per-phase padded counters, zeroed by prologue
#define SUB_U  ((TSTEPS + 2) * 8 * 32)
#define SUP_U  ((TSTEPS + 2) * 32)
#define GO_U   (8 * 32)

typedef __bf16 bf16x8 __attribute__((ext_vector_type(8)));
typedef float  f32x4  __attribute__((ext_vector_type(4)));
typedef unsigned long long u64x2 __attribute__((ext_vector_type(2)));
typedef unsigned int uint;
typedef unsigned long long u64;

__device__ __forceinline__ unsigned short rne_bf16(float f) {
    uint u = __float_as_uint(f);
    return (unsigned short)((u + 0x7fffu + ((u >> 16) & 1u)) >> 16);
}
__device__ __forceinline__ float bf2f(unsigned short s) {
    return __uint_as_float(((uint)s) << 16);
}

// device-coherent (agent-scope, L2-bypassing) accesses — no fences needed
__device__ __forceinline__ u64 cload(const __bf16* p) {
    return __hip_atomic_load((const u64*)p, __ATOMIC_RELAXED,
                             __HIP_MEMORY_SCOPE_AGENT);
}
__device__ __forceinline__ void cstore32(__bf16* p, uint v) {
    __hip_atomic_store((uint*)p, v, __ATOMIC_RELAXED,
                       __HIP_MEMORY_SCOPE_AGENT);
}

__global__ __launch_bounds__(256) void zero_sync(uint* __restrict__ p) {
    const int i = blockIdx.x * 256 + threadIdx.x;
    if (i < SUB_U + SUP_U + GO_U) p[i] = 0u;
}

// Fence-free two-level grid barrier: relaxed atomics only.
// Preceding __syncthreads drains each thread's coherent stores (hipcc emits
// vmcnt(0) before s_barrier), so arrival implies this block's data is visible.
__device__ __forceinline__ void gridbar(uint* __restrict__ SUB,
                                        uint* __restrict__ SUP,
                                        uint* __restrict__ GO, uint phase) {
    __syncthreads();
    if (threadIdx.x == 0) {
        const uint g = blockIdx.x & 7u;
        uint o = __hip_atomic_fetch_add(&SUB[(phase * 8u + g) * 32u], 1u,
                                        __ATOMIC_RELAXED, __HIP_MEMORY_SCOPE_AGENT);
        if (o == (NBLK / 8 - 1)) {
            uint s = __hip_atomic_fetch_add(&SUP[phase * 32u], 1u,
                                            __ATOMIC_RELAXED, __HIP_MEMORY_SCOPE_AGENT);
            if (s == 7u) {
                #pragma unroll
                for (int i = 0; i < 8; ++i)
                    __hip_atomic_store(&GO[i * 32], phase,
                                       __ATOMIC_RELAXED, __HIP_MEMORY_SCOPE_AGENT);
            }
        }
        uint* myg = &GO[g * 32u];
        while (__hip_atomic_load(myg, __ATOMIC_RELAXED,
                                 __HIP_MEMORY_SCOPE_AGENT) < phase)
            __builtin_amdgcn_s_sleep(4);
    }
    __syncthreads();
}

// 128 blocks x 256 thr (4 waves). Block bx owns h-cols [bx*8,+8) x 4 gates
// = 32 N-cols, full K (wave w: k in [w*384,+384)). W hi/lo in ~192 VGPR/lane.
__global__ __launch_bounds__(256, 1) void lstm_persist(
    const float* __restrict__ x,                       // [T,B,E]
    const float* __restrict__ Wi, const float* __restrict__ Wo,
    const float* __restrict__ Wf, const float* __restrict__ Wm,  // [KDIM,HDIM]
    const float* __restrict__ bi, const float* __restrict__ bo,
    const float* __restrict__ bfp, const float* __restrict__ bm, // [HDIM]
    float* __restrict__ out,                           // [B,T,H]
    __bf16* __restrict__ abase,                        // 4 planes of APLANE
    uint* __restrict__ SUB, uint* __restrict__ SUP, uint* __restrict__ GO)
{
    __shared__ float zbuf[4][64][33];   // [wave][row][32 cols + pad]

    const int tid  = threadIdx.x;
    const int bx   = blockIdx.x;
    const int lane = tid & 63;
    const int w    = tid >> 6;          // wave id = K-slice id
    const int l15  = lane & 15;
    const int q    = lane >> 4;

    // ---- load W (hi/lo split) into registers ----
    const int g0  = l15 >> 3, j = l15 & 7;
    const int col = bx * 8 + j;
    const float* Wg0 = (g0 == 0) ? Wi : Wo;
    const float* Wg1 = (g0 == 0) ? Wf : Wm;
    bf16x8 wh0[12], wl0[12], wh1[12], wl1[12];
    #pragma unroll
    for (int kk = 0; kk < 12; ++kk) {
        unsigned short uh0[8], ul0[8], uh1[8], ul1[8];
        #pragma unroll
        for (int e = 0; e < 8; ++e) {
            const int k = w * KW + kk * 32 + q * 8 + e;
            const float v0 = Wg0[(size_t)k * HDIM + col];
            const float v1 = Wg1[(size_t)k * HDIM + col];
            const unsigned short h0 = rne_bf16(v0);
            const unsigned short h1 = rne_bf16(v1);
            uh0[e] = h0; ul0[e] = rne_bf16(v0 - bf2f(h0));
            uh1[e] = h1; ul1[e] = rne_bf16(v1 - bf2f(h1));
        }
        wh0[kk] = *(bf16x8*)uh0; wl0[kk] = *(bf16x8*)ul0;
        wh1[kk] = *(bf16x8*)uh1; wl1[kk] = *(bf16x8*)ul1;
    }

    // ---- per-thread gate mapping: 2 outputs (rows gb, gb+32; col ghc) ----
    const int gb  = tid >> 3;           // 0..31
    const int gj  = tid & 7;
    const int ghc = bx * 8 + gj;
    float bia[4];
    bia[0] = bi[ghc]; bia[1] = bo[ghc]; bia[2] = bfp[ghc]; bia[3] = bm[ghc];
    float c0 = 0.0f, c1 = 0.0f;

    // ---- init A[0]: x0 (hi/lo, packed-pair coherent stores) + h0 = 0 ----
    {
        __bf16* AH0 = abase;
        __bf16* AL0 = abase + APLANE;
        const int flat = bx * 256 + tid;          // [64][512] x-part
        const int b = flat >> 9, e = flat & 511;  // e parity == tid parity
        const float v = x[flat];                  // t = 0
        const unsigned short xh = rne_bf16(v);
        const unsigned short xl = rne_bf16(v - bf2f(xh));
        const unsigned short ph = (unsigned short)__shfl_xor((int)xh, 1);
        const unsigned short pl = (unsigned short)__shfl_xor((int)xl, 1);
        if ((tid & 1) == 0)
            cstore32(&AH0[b * KDIM + e], (uint)xh | ((uint)ph << 16));
        else
            cstore32(&AL0[b * KDIM + e - 1], (uint)pl | ((uint)xl << 16));
        // h-part zeros: one u32 (2 cols) per thread per plane, 128 blks cover all
        const int idx2 = bx * 256 + tid;          // over 32768 u32 slots
        const int b2 = idx2 >> 9, cp = idx2 & 511;
        cstore32(&AH0[b2 * KDIM + 512 + cp * 2], 0u);
        cstore32(&AL0[b2 * KDIM + 512 + cp * 2], 0u);
    }
    gridbar(SUB, SUP, GO, 1u);

    // ---- time loop ----
    for (int t = 0; t < TSTEPS; ++t) {
        const int cur = t & 1;
        const __bf16* AH = abase + (size_t)(2 * cur) * APLANE;
        const __bf16* AL = AH + APLANE;
        __bf16* AHn = abase + (size_t)(2 * (cur ^ 1)) * APLANE;
        __bf16* ALn = AHn + APLANE;

        // x[t+1] -> next A buffer (overlaps MFMA; nobody reads AHn this phase)
        if (t + 1 < TSTEPS) {
            const int flat = bx * 256 + tid;
            const int b = flat >> 9, e = flat & 511;
            const float v = x[(size_t)(t + 1) * (BSZ * EDIM) + flat];
            const unsigned short xh = rne_bf16(v);
            const unsigned short xl = rne_bf16(v - bf2f(xh));
            const unsigned short ph = (unsigned short)__shfl_xor((int)xh, 1);
            const unsigned short pl = (unsigned short)__shfl_xor((int)xl, 1);
            if ((tid & 1) == 0)
                cstore32(&AHn[b * KDIM + e], (uint)xh | ((uint)ph << 16));
            else
                cstore32(&ALn[b * KDIM + e - 1], (uint)pl | ((uint)xl << 16));
        }

        // MFMA: 4 m-tiles x 2 n-tiles, 3-term hi/lo; A via coherent 8B loads
        f32x4 acc[4][2];
        #pragma unroll
        for (int m = 0; m < 4; ++m)
            #pragma unroll
            for (int nt = 0; nt < 2; ++nt) acc[m][nt] = (f32x4){0.f, 0.f, 0.f, 0.f};

        #pragma unroll
        for (int kk = 0; kk < 12; ++kk) {
            const int kof = w * KW + kk * 32 + q * 8;
            bf16x8 ah[4], al[4];
            #pragma unroll
            for (int m = 0; m < 4; ++m) {
                const size_t off = (size_t)(m * 16 + l15) * KDIM + kof;
                u64x2 vh, vl;
                vh[0] = cload(&AH[off]);     vh[1] = cload(&AH[off + 4]);
                vl[0] = cload(&AL[off]);     vl[1] = cload(&AL[off + 4]);
                ah[m] = __builtin_bit_cast(bf16x8, vh);
                al[m] = __builtin_bit_cast(bf16x8, vl);
            }
            #pragma unroll
            for (int m = 0; m < 4; ++m) {
                acc[m][0] = __builtin_amdgcn_mfma_f32_16x16x32_bf16(ah[m], wh0[kk], acc[m][0], 0, 0, 0);
                acc[m][1] = __builtin_amdgcn_mfma_f32_16x16x32_bf16(ah[m], wh1[kk], acc[m][1], 0, 0, 0);
                acc[m][0] = __builtin_amdgcn_mfma_f32_16x16x32_bf16(ah[m], wl0[kk], acc[m][0], 0, 0, 0);
                acc[m][1] = __builtin_amdgcn_mfma_f32_16x16x32_bf16(ah[m], wl1[kk], acc[m][1], 0, 0, 0);
                acc[m][0] = __builtin_amdgcn_mfma_f32_16x16x32_bf16(al[m], wh0[kk], acc[m][0], 0, 0, 0);
                acc[m][1] = __builtin_amdgcn_mfma_f32_16x16x32_bf16(al[m], wh1[kk], acc[m][1], 0, 0, 0);
            }
        }

        // partials -> LDS  (C layout: col=lane&15, row=(lane>>4)*4+r)
        __syncthreads();
        #pragma unroll
        for (int m = 0; m < 4; ++m)
            #pragma unroll
            for (int nt = 0; nt < 2; ++nt)
                #pragma unroll
                for (int r = 0; r < 4; ++r)
                    zbuf[w][m * 16 + q * 4 + r][nt * 16 + l15] = acc[m][nt][r];
        __syncthreads();

        // gates: 2 outputs per thread (rows gb, gb+32)
        #pragma unroll
        for (int half = 0; half < 2; ++half) {
            const int b = gb + half * 32;
            float z[4];
            #pragma unroll
            for (int gg = 0; gg < 4; ++gg)
                z[gg] = zbuf[0][b][gg * 8 + gj] + zbuf[1][b][gg * 8 + gj]
                      + zbuf[2][b][gg * 8 + gj] + zbuf[3][b][gg * 8 + gj] + bia[gg];
            const float ig = 1.0f / (1.0f + expf(-z[0]));
            const float og = 1.0f / (1.0f + expf(-z[1]));
            const float fg = 1.0f / (1.0f + expf(-z[2]));
            const float mg = tanhf(z[3]);
            float& cr = half ? c1 : c0;
            cr = fg * cr + ig * mg;
            const float hv = og * tanhf(cr);
            out[((size_t)b * TSTEPS + t) * HDIM + ghc] = hv;

            // h -> next A (packed-pair coherent stores; pairs share row b)
            const unsigned short hh = rne_bf16(hv);
            const unsigned short hl = rne_bf16(hv - bf2f(hh));
            const unsigned short ph = (unsigned short)__shfl_xor((int)hh, 1);
            const unsigned short pl = (unsigned short)__shfl_xor((int)hl, 1);
            if ((gj & 1) == 0)
                cstore32(&AHn[b * KDIM + 512 + ghc], (uint)hh | ((uint)ph << 16));
            else
                cstore32(&ALn[b * KDIM + 512 + ghc - 1], (uint)pl | ((uint)hl << 16));
        }

        if (t + 1 < TSTEPS) gridbar(SUB, SUP, GO, (uint)(t + 2));
    }
}

extern "C" void kernel_launch(void* const* d_in, const int* in_sizes, int n_in,
                              void* d_out, int out_size, void* d_ws, size_t ws_size,
                              hipStream_t stream) {
    const float* x   = (const float*)d_in[0];
    const float* Wi  = (const float*)d_in[1];
    const float* bi  = (const float*)d_in[2];
    const float* Wo  = (const float*)d_in[3];
    const float* bo  = (const float*)d_in[4];
    const float* Wf  = (const float*)d_in[5];
    const float* bfp = (const float*)d_in[6];
    const float* Wm  = (const float*)d_in[7];
    const float* bm  = (const float*)d_in[8];
    float* out = (float*)d_out;

    // ws: 4 bf16 A-planes (786,432 B) | SUB | SUP | GO  (~1.4 MB total)
    __bf16* abase = (__bf16*)d_ws;
    uint*   SUB   = (uint*)((char*)d_ws + 4 * (size_t)APLANE * 2);
    uint*   SUP   = SUB + SUB_U;
    uint*   GO    = SUP + SUP_U;

    const int zn = SUB_U + SUP_U + GO_U;
    zero_sync<<<(zn + 255) / 256, 256, 0, stream>>>(SUB);

    lstm_persist<<<NBLK, 256, 0, stream>>>(
        x, Wi, Wo, Wf, Wm, bi, bo, bfp, bm, out, abase, SUB, SUP, GO);
}